// Round 1
// baseline (950.183 us; speedup 1.0000x reference)
//
#include <hip/hip_runtime.h>
#include <hip/hip_bf16.h>
#include <cstdint>
#include <cstddef>

// ---------------- problem dims ----------------
#define BATCH 65536
#define DCDIM 512
#define DIDIM 512
#define DTDIM 256

typedef __attribute__((ext_vector_type(8))) short short8;   // 8 bf16 = 4 VGPR (MFMA A/B frag)
typedef __attribute__((ext_vector_type(4))) float floatx4;  // MFMA C/D frag

// ---------------- ws layout (bytes) ----------------
// total ~207.4 MB
constexpr size_t WS_WA   = 0;                              // 1536x512 bf16 (W_ih rows i,g,o)
constexpr size_t WS_WCAT = WS_WA   + (size_t)1536*512*2;   // 2048x768 bf16 ([W_hh | W_ih[:,:256]])
constexpr size_t WS_WFC  = WS_WCAT + (size_t)2048*768*2;   // 1024x512 bf16
constexpr size_t WS_BIAS = WS_WFC  + (size_t)1024*512*2;   // 2048 f32 (b_ih + b_hh)
constexpr size_t WS_CNT  = WS_BIAS + (size_t)2048*4;       // 1 int (both-count)
constexpr size_t WS_LIST = WS_CNT  + 256;                  // 65536 int (both-row indices)
constexpr size_t WS_H1   = WS_LIST + (size_t)BATCH*4;      // BATCH x 512 bf16
constexpr size_t WS_C1   = WS_H1   + (size_t)BATCH*512*2;  // BATCH x 512 bf16
constexpr size_t WS_H2   = WS_C1   + (size_t)BATCH*512*2;  // BATCH x 512 bf16

// ---------------- helpers ----------------
__device__ __forceinline__ unsigned short f2b(float x) {   // fp32 -> bf16 RNE
  unsigned int u = __builtin_bit_cast(unsigned int, x);
  u += 0x7FFFu + ((u >> 16) & 1u);
  return (unsigned short)(u >> 16);
}
__device__ __forceinline__ float b2f(unsigned short h) {
  unsigned int u = ((unsigned int)h) << 16;
  return __builtin_bit_cast(float, u);
}
__device__ __forceinline__ float sigm(float x) { return 1.0f / (1.0f + __expf(-x)); }

__device__ __forceinline__ uint4 pack8(float4 a, float4 b) {
  uint4 w;
  w.x = (unsigned)f2b(a.x) | ((unsigned)f2b(a.y) << 16);
  w.y = (unsigned)f2b(a.z) | ((unsigned)f2b(a.w) << 16);
  w.z = (unsigned)f2b(b.x) | ((unsigned)f2b(b.y) << 16);
  w.w = (unsigned)f2b(b.z) | ((unsigned)f2b(b.w) << 16);
  return w;
}

// ---------------- prep: convert/rearrange weights to bf16, bias0, zero counter ----------------
__global__ void prep_kernel(const float* __restrict__ Wih, const float* __restrict__ Whh,
                            const float* __restrict__ bih, const float* __restrict__ bhh,
                            const float* __restrict__ Wfc,
                            unsigned short* __restrict__ wa, unsigned short* __restrict__ wcat,
                            unsigned short* __restrict__ wfc, float* __restrict__ bias0,
                            int* __restrict__ cnt) {
  int idx = blockIdx.x * blockDim.x + threadIdx.x;
  if (idx == 0) *cnt = 0;
  const int nA = 1536 * 512;
  const int nB = 2048 * 768;
  const int nC = 1024 * 512;
  if (idx < nA) {
    int r = idx >> 9, c = idx & 511;
    int sr = (r < 512) ? r : (r + 512);      // rows: i(0..511), g(1024..1535), o(1536..2047)
    wa[idx] = f2b(Wih[(size_t)sr * 512 + c]);
  } else if (idx < nA + nB) {
    int j = idx - nA;
    int r = j / 768, c = j - r * 768;
    float v = (c < 512) ? Whh[(size_t)r * 512 + c] : Wih[(size_t)r * 512 + (c - 512)];
    wcat[j] = f2b(v);
  } else if (idx < nA + nB + nC) {
    int j = idx - nA - nB;
    wfc[j] = f2b(Wfc[j]);
  } else if (idx < nA + nB + nC + 2048) {
    int j = idx - nA - nB - nC;
    bias0[j] = bih[j] + bhh[j];
  }
}

// ---------------- prepass: compact list of rows with both image & text present ----------------
__global__ void prepass_kernel(const int* __restrict__ imask, const int* __restrict__ tmask,
                               int* __restrict__ cnt, int* __restrict__ list) {
  int m = blockIdx.x * blockDim.x + threadIdx.x;
  if (m < BATCH) {
    if (imask[m] == 0 && tmask[m] == 0) {
      int p = atomicAdd(cnt, 1);
      list[p] = m;
    }
  }
}

// ---------------- phase A: step0 fused GEMM(i,g,o gates) + LSTM -> h1, c1 ----------------
// grid: 8192 = jb(8 slow) * my(1024 fast); block 256 = 4 waves.
// per block: rows m0..m0+63, hidden cols j0..j0+63; 3 gate tiles of 64x64.
__global__ __launch_bounds__(256) void phaseA_kernel(
    const float* __restrict__ img, const float* __restrict__ txt,
    const int* __restrict__ imask, const int* __restrict__ tmask,
    const unsigned short* __restrict__ Wa, const float* __restrict__ bias0,
    unsigned short* __restrict__ h1, unsigned short* __restrict__ c1) {
  __shared__ __align__(16) char smem[50688];      // union: Xs(8K)+Ws(24K) | Gs 3*64*66*4
  __shared__ int sel[64];
  char* xs = smem;              // 64 rows * 128B (swizzled granules)
  char* wsm = smem + 8192;      // 192 rows * 128B
  float (*Gs)[64][66] = (float (*)[64][66])smem;

  int tid = threadIdx.x;
  int bx = blockIdx.x;
  int my = bx & 1023, jb = bx >> 10;
  int m0 = my * 64, j0 = jb * 64;
  int wave = tid >> 6, lane = tid & 63, lhi = lane >> 4, llo = lane & 15;

  if (tid < 64) {
    int m = m0 + tid;
    sel[tid] = (imask[m] == 0) ? 0 : ((tmask[m] == 0) ? 1 : 2);
  }
  __syncthreads();

  floatx4 acc[4][3];
  floatx4 zz = {0.f, 0.f, 0.f, 0.f};
#pragma unroll
  for (int a = 0; a < 4; ++a)
#pragma unroll
    for (int b = 0; b < 3; ++b) acc[a][b] = zz;

  for (int kc = 0; kc < 8; ++kc) {
    // stage X (dest-linear slots, source granule XOR-permuted -> conflict-free writes)
#pragma unroll
    for (int i2 = 0; i2 < 2; ++i2) {
      int f = i2 * 256 + tid;
      int r = f >> 3, sw = f & 7, g = sw ^ (r & 7);
      int kk = kc * 64 + g * 8;
      float4 v0 = {0.f, 0.f, 0.f, 0.f}, v1 = {0.f, 0.f, 0.f, 0.f};
      int s = sel[r];
      if (s == 0) {
        const float4* p = (const float4*)(img + (size_t)(m0 + r) * DIDIM + kk);
        v0 = p[0]; v1 = p[1];
      } else if (s == 1 && kk < DTDIM) {
        const float4* p = (const float4*)(txt + (size_t)(m0 + r) * DTDIM + kk);
        v0 = p[0]; v1 = p[1];
      }
      *(uint4*)(xs + r * 128 + sw * 16) = pack8(v0, v1);
    }
    // stage W: 192 rows (3 gates x 64 cols)
#pragma unroll
    for (int i2 = 0; i2 < 6; ++i2) {
      int f = i2 * 256 + tid;
      int rr = f >> 3, sw = f & 7, g = sw ^ (rr & 7);
      int lg = rr >> 6, jj = rr & 63;
      const uint4* src = (const uint4*)(Wa + ((size_t)(lg * 512 + j0 + jj)) * 512 + kc * 64 + g * 8);
      *(uint4*)(wsm + rr * 128 + sw * 16) = *src;
    }
    __syncthreads();
#pragma unroll
    for (int ks = 0; ks < 2; ++ks) {
      short8 afr[4];
#pragma unroll
      for (int ri = 0; ri < 4; ++ri) {
        int row = ri * 16 + llo;
        int sw = (ks * 4 + lhi) ^ (row & 7);
        afr[ri] = *(const short8*)(xs + row * 128 + sw * 16);
      }
#pragma unroll
      for (int s = 0; s < 3; ++s) {
        int u = 3 * wave + s;
        int lg = u >> 2, ci = u & 3;
        int rr = lg * 64 + ci * 16 + llo;
        int sw = (ks * 4 + lhi) ^ (rr & 7);
        short8 bfr = *(const short8*)(wsm + rr * 128 + sw * 16);
#pragma unroll
        for (int ri = 0; ri < 4; ++ri)
          acc[ri][s] = __builtin_amdgcn_mfma_f32_16x16x32_bf16(afr[ri], bfr, acc[ri][s], 0, 0, 0);
      }
    }
    __syncthreads();
  }
  // exchange gate tiles through LDS (cross-wave: each wave holds parts of different gates)
#pragma unroll
  for (int s = 0; s < 3; ++s) {
    int u = 3 * wave + s;
    int lg = u >> 2, ci = u & 3;
#pragma unroll
    for (int ri = 0; ri < 4; ++ri)
#pragma unroll
      for (int p = 0; p < 4; ++p)
        Gs[lg][ri * 16 + lhi * 4 + p][ci * 16 + llo] = acc[ri][s][p];
  }
  __syncthreads();
  {
    int m = tid >> 2;
    int jbase = (tid & 3) * 16;
    size_t rowoff = (size_t)(m0 + m) * DCDIM + j0;
#pragma unroll
    for (int q = 0; q < 16; ++q) {
      int jj = jbase + q;
      int j = j0 + jj;
      float iv = Gs[0][m][jj] + bias0[j];
      float gv = Gs[1][m][jj] + bias0[1024 + j];
      float ov = Gs[2][m][jj] + bias0[1536 + j];
      float iS = sigm(iv), gT = tanhf(gv), oS = sigm(ov);
      float cv = iS * gT;            // c0 = 0 -> f gate irrelevant in step 0
      float hv = oS * tanhf(cv);
      c1[rowoff + jj] = f2b(cv);
      h1[rowoff + jj] = f2b(hv);
    }
  }
}

// ---------------- phase B: step1 (compacted to both-rows) -> h2 ----------------
// gates = [h1 | txt] @ [W_hh | W_ih[:,:256]]^T + bias0 ; K = 768; 4 gate tiles 64x64 (wave = gate)
__global__ __launch_bounds__(256) void phaseB_kernel(
    const float* __restrict__ txt,
    const unsigned short* __restrict__ h1, const unsigned short* __restrict__ c1,
    const unsigned short* __restrict__ Wcat, const float* __restrict__ bias0,
    const int* __restrict__ cnt, const int* __restrict__ list,
    unsigned short* __restrict__ h2) {
  __shared__ __align__(16) char smem[67584];      // union: Xs(8K)+Ws(32K) | Gs 4*64*66*4
  __shared__ int rowmap[64];
  __shared__ int validr[64];
  char* xs = smem;
  char* wsm = smem + 8192;     // 256 rows * 128B
  float (*Gs)[64][66] = (float (*)[64][66])smem;

  int tid = threadIdx.x;
  int bx = blockIdx.x;
  int my = bx & 1023, jb = bx >> 10;
  int n = *cnt;
  int nbk = (n + 63) >> 6;
  if (my >= nbk) return;      // block-uniform early exit (compaction)
  int j0 = jb * 64;
  int wave = tid >> 6, lane = tid & 63, lhi = lane >> 4, llo = lane & 15;

  if (tid < 64) {
    int p = my * 64 + tid;
    int v = (p < n) ? 1 : 0;
    validr[tid] = v;
    rowmap[tid] = list[v ? p : 0];
  }
  __syncthreads();

  floatx4 acc[4][4];
  floatx4 zz = {0.f, 0.f, 0.f, 0.f};
#pragma unroll
  for (int a = 0; a < 4; ++a)
#pragma unroll
    for (int b = 0; b < 4; ++b) acc[a][b] = zz;

  for (int kc = 0; kc < 12; ++kc) {
    // X = [h1 | txt]
#pragma unroll
    for (int i2 = 0; i2 < 2; ++i2) {
      int f = i2 * 256 + tid;
      int r = f >> 3, sw = f & 7, g = sw ^ (r & 7);
      int gm = rowmap[r];
      uint4 w;
      if (kc < 8) {
        w = *(const uint4*)(h1 + (size_t)gm * DCDIM + kc * 64 + g * 8);
      } else {
        int kk = (kc - 8) * 64 + g * 8;
        const float4* p = (const float4*)(txt + (size_t)gm * DTDIM + kk);
        w = pack8(p[0], p[1]);
      }
      *(uint4*)(xs + r * 128 + sw * 16) = w;
    }
    // W: 256 rows (4 gates x 64 cols), row length 768
#pragma unroll
    for (int i2 = 0; i2 < 8; ++i2) {
      int f = i2 * 256 + tid;
      int rr = f >> 3, sw = f & 7, g = sw ^ (rr & 7);
      int gg = rr >> 6, jj = rr & 63;
      const uint4* src = (const uint4*)(Wcat + ((size_t)(gg * 512 + j0 + jj)) * 768 + kc * 64 + g * 8);
      *(uint4*)(wsm + rr * 128 + sw * 16) = *src;
    }
    __syncthreads();
#pragma unroll
    for (int ks = 0; ks < 2; ++ks) {
      short8 afr[4];
#pragma unroll
      for (int ri = 0; ri < 4; ++ri) {
        int row = ri * 16 + llo;
        int sw = (ks * 4 + lhi) ^ (row & 7);
        afr[ri] = *(const short8*)(xs + row * 128 + sw * 16);
      }
#pragma unroll
      for (int ci = 0; ci < 4; ++ci) {
        int rr = wave * 64 + ci * 16 + llo;
        int sw = (ks * 4 + lhi) ^ (rr & 7);
        short8 bfr = *(const short8*)(wsm + rr * 128 + sw * 16);
#pragma unroll
        for (int ri = 0; ri < 4; ++ri)
          acc[ri][ci] = __builtin_amdgcn_mfma_f32_16x16x32_bf16(afr[ri], bfr, acc[ri][ci], 0, 0, 0);
      }
    }
    __syncthreads();
  }
#pragma unroll
  for (int ci = 0; ci < 4; ++ci)
#pragma unroll
    for (int ri = 0; ri < 4; ++ri)
#pragma unroll
      for (int p = 0; p < 4; ++p)
        Gs[wave][ri * 16 + lhi * 4 + p][ci * 16 + llo] = acc[ri][ci][p];
  __syncthreads();
  {
    int m = tid >> 2;
    if (validr[m]) {
      int gm = rowmap[m];
      int jbase = (tid & 3) * 16;
#pragma unroll
      for (int q = 0; q < 16; ++q) {
        int jj = jbase + q;
        int j = j0 + jj;
        float iv = Gs[0][m][jj] + bias0[j];
        float fv = Gs[1][m][jj] + bias0[512 + j];
        float gv = Gs[2][m][jj] + bias0[1024 + j];
        float ov = Gs[3][m][jj] + bias0[1536 + j];
        float iS = sigm(iv), fS = sigm(fv), gT = tanhf(gv), oS = sigm(ov);
        float c1v = b2f(c1[(size_t)gm * DCDIM + j]);
        float c2 = fS * c1v + iS * gT;
        float h2v = oS * tanhf(c2);
        h2[(size_t)gm * DCDIM + j] = f2b(h2v);
      }
    }
  }
}

// ---------------- phase C: out = h_final @ W_fc^T + b_fc ----------------
// per block: 64 rows x 128 out-cols; wave w covers col-frags {2w, 2w+1}
__global__ __launch_bounds__(256) void phaseC_kernel(
    const int* __restrict__ imask, const int* __restrict__ tmask,
    const unsigned short* __restrict__ h1, const unsigned short* __restrict__ h2,
    const unsigned short* __restrict__ Wfc, const float* __restrict__ bfc,
    float* __restrict__ out) {
  __shared__ __align__(16) char smem[24576];   // Xs 8K + Ws 16K
  __shared__ int both[64];
  char* xs = smem;
  char* wsm = smem + 8192;    // 128 rows * 128B
  int tid = threadIdx.x;
  int bx = blockIdx.x;
  int my = bx & 1023, nb = bx >> 10;
  int m0 = my * 64, n0 = nb * 128;
  int wave = tid >> 6, lane = tid & 63, lhi = lane >> 4, llo = lane & 15;
  if (tid < 64) {
    int m = m0 + tid;
    both[tid] = (imask[m] == 0 && tmask[m] == 0) ? 1 : 0;
  }
  __syncthreads();

  floatx4 acc[4][2];
  floatx4 zz = {0.f, 0.f, 0.f, 0.f};
#pragma unroll
  for (int a = 0; a < 4; ++a) { acc[a][0] = zz; acc[a][1] = zz; }

  for (int kc = 0; kc < 8; ++kc) {
#pragma unroll
    for (int i2 = 0; i2 < 2; ++i2) {
      int f = i2 * 256 + tid;
      int r = f >> 3, sw = f & 7, g = sw ^ (r & 7);
      const unsigned short* base = both[r] ? h2 : h1;
      uint4 w = *(const uint4*)(base + (size_t)(m0 + r) * DCDIM + kc * 64 + g * 8);
      *(uint4*)(xs + r * 128 + sw * 16) = w;
    }
#pragma unroll
    for (int i2 = 0; i2 < 4; ++i2) {
      int f = i2 * 256 + tid;
      int rr = f >> 3, sw = f & 7, g = sw ^ (rr & 7);
      const uint4* src = (const uint4*)(Wfc + ((size_t)(n0 + rr)) * 512 + kc * 64 + g * 8);
      *(uint4*)(wsm + rr * 128 + sw * 16) = *src;
    }
    __syncthreads();
#pragma unroll
    for (int ks = 0; ks < 2; ++ks) {
      short8 afr[4];
#pragma unroll
      for (int ri = 0; ri < 4; ++ri) {
        int row = ri * 16 + llo;
        int sw = (ks * 4 + lhi) ^ (row & 7);
        afr[ri] = *(const short8*)(xs + row * 128 + sw * 16);
      }
#pragma unroll
      for (int cl = 0; cl < 2; ++cl) {
        int rr = (wave * 2 + cl) * 16 + llo;
        int sw = (ks * 4 + lhi) ^ (rr & 7);
        short8 bfr = *(const short8*)(wsm + rr * 128 + sw * 16);
#pragma unroll
        for (int ri = 0; ri < 4; ++ri)
          acc[ri][cl] = __builtin_amdgcn_mfma_f32_16x16x32_bf16(afr[ri], bfr, acc[ri][cl], 0, 0, 0);
      }
    }
    __syncthreads();
  }
#pragma unroll
  for (int cl = 0; cl < 2; ++cl) {
    int nn = n0 + (wave * 2 + cl) * 16 + llo;
    float bb = bfc[nn];
#pragma unroll
    for (int ri = 0; ri < 4; ++ri)
#pragma unroll
      for (int p = 0; p < 4; ++p) {
        int mm = m0 + ri * 16 + lhi * 4 + p;
        out[(size_t)mm * 1024 + nn] = acc[ri][cl][p] + bb;
      }
  }
}

// ---------------- launcher ----------------
extern "C" void kernel_launch(void* const* d_in, const int* in_sizes, int n_in,
                              void* d_out, int out_size, void* d_ws, size_t ws_size,
                              hipStream_t stream) {
  const float* img  = (const float*)d_in[0];
  const float* txt  = (const float*)d_in[1];
  const int* imask  = (const int*)d_in[2];
  const int* tmask  = (const int*)d_in[3];
  const float* Wih  = (const float*)d_in[4];
  const float* Whh  = (const float*)d_in[5];
  const float* bih  = (const float*)d_in[6];
  const float* bhh  = (const float*)d_in[7];
  const float* Wfc  = (const float*)d_in[8];
  const float* bfc  = (const float*)d_in[9];
  float* out = (float*)d_out;

  char* ws = (char*)d_ws;
  unsigned short* wa   = (unsigned short*)(ws + WS_WA);
  unsigned short* wcat = (unsigned short*)(ws + WS_WCAT);
  unsigned short* wfc  = (unsigned short*)(ws + WS_WFC);
  float* bias0         = (float*)(ws + WS_BIAS);
  int* cnt             = (int*)(ws + WS_CNT);
  int* list            = (int*)(ws + WS_LIST);
  unsigned short* h1   = (unsigned short*)(ws + WS_H1);
  unsigned short* c1   = (unsigned short*)(ws + WS_C1);
  unsigned short* h2   = (unsigned short*)(ws + WS_H2);

  // 1536*512 + 2048*768 + 1024*512 + 2048 = 2885632 elements -> 11272 blocks
  prep_kernel<<<11272, 256, 0, stream>>>(Wih, Whh, bih, bhh, Wfc, wa, wcat, wfc, bias0, cnt);
  prepass_kernel<<<256, 256, 0, stream>>>(imask, tmask, cnt, list);
  phaseA_kernel<<<8192, 256, 0, stream>>>(img, txt, imask, tmask, wa, bias0, h1, c1);
  phaseB_kernel<<<8192, 256, 0, stream>>>(txt, h1, c1, wcat, bias0, cnt, list, h2);
  phaseC_kernel<<<8192, 256, 0, stream>>>(imask, tmask, h1, h2, wfc, bfc, out);
}

// Round 10
// 913.591 us; speedup vs baseline: 1.0401x; 1.0401x over previous
//
#include <hip/hip_runtime.h>
#include <hip/hip_bf16.h>
#include <cstdint>
#include <cstddef>

// ---------------- problem dims ----------------
#define BATCH 65536
#define DCDIM 512
#define DIDIM 512
#define DTDIM 256

typedef __attribute__((ext_vector_type(8))) short short8;   // 8 bf16 = 4 VGPR (MFMA A/B frag)
typedef __attribute__((ext_vector_type(4))) float floatx4;  // MFMA C/D frag

// ---------------- ws layout (bytes), total ~207.4 MB ----------------
constexpr size_t WS_WA   = 0;                              // 1536x512 bf16 (W_ih rows i,g,o)
constexpr size_t WS_WCAT = WS_WA   + (size_t)1536*512*2;   // 2048x768 bf16 ([W_hh | W_ih[:,:256]])
constexpr size_t WS_WFC  = WS_WCAT + (size_t)2048*768*2;   // 1024x512 bf16
constexpr size_t WS_BIAS = WS_WFC  + (size_t)1024*512*2;   // 2048 f32 (b_ih + b_hh)
constexpr size_t WS_CNT  = WS_BIAS + (size_t)2048*4;       // 1 int (both-count)
constexpr size_t WS_LIST = WS_CNT  + 256;                  // 65536 int (both-row indices)
constexpr size_t WS_H1   = WS_LIST + (size_t)BATCH*4;      // BATCH x 512 bf16
constexpr size_t WS_C1   = WS_H1   + (size_t)BATCH*512*2;  // BATCH x 512 bf16
constexpr size_t WS_H2   = WS_C1   + (size_t)BATCH*512*2;  // BATCH x 512 bf16; ALIASED with X0:
                                                           //   X0 live only in phaseA; h2 born in phaseB

// ---------------- helpers ----------------
__device__ __forceinline__ unsigned short f2b(float x) {   // fp32 -> bf16 RNE
  unsigned int u = __builtin_bit_cast(unsigned int, x);
  u += 0x7FFFu + ((u >> 16) & 1u);
  return (unsigned short)(u >> 16);
}
__device__ __forceinline__ unsigned pack2(float a, float b) {
  return (unsigned)f2b(a) | ((unsigned)f2b(b) << 16);
}
__device__ __forceinline__ float b2f(unsigned short h) {
  unsigned int u = ((unsigned int)h) << 16;
  return __builtin_bit_cast(float, u);
}
__device__ __forceinline__ float sigm(float x) { return 1.0f / (1.0f + __expf(-x)); }

__device__ __forceinline__ uint4 pack8(float4 a, float4 b) {
  uint4 w;
  w.x = pack2(a.x, a.y); w.y = pack2(a.z, a.w);
  w.z = pack2(b.x, b.y); w.w = pack2(b.z, b.w);
  return w;
}

// async global->LDS, 16B per lane; LDS dest wave-uniform base + lane*16
__device__ __forceinline__ void gload16(const void* g, void* l) {
  __builtin_amdgcn_global_load_lds((__attribute__((address_space(1))) void*)g,
                                   (__attribute__((address_space(3))) void*)l, 16, 0, 0);
}

// ---------------- prep: weights -> bf16 (rearranged), bias0, zero counter ----------------
__global__ void prep_kernel(const float* __restrict__ Wih, const float* __restrict__ Whh,
                            const float* __restrict__ bih, const float* __restrict__ bhh,
                            const float* __restrict__ Wfc,
                            unsigned short* __restrict__ wa, unsigned short* __restrict__ wcat,
                            unsigned short* __restrict__ wfc, float* __restrict__ bias0,
                            int* __restrict__ cnt) {
  int idx = blockIdx.x * blockDim.x + threadIdx.x;
  if (idx == 0) *cnt = 0;
  const int nA = 1536 * 512;
  const int nB = 2048 * 768;
  const int nC = 1024 * 512;
  if (idx < nA) {
    int r = idx >> 9, c = idx & 511;
    int sr = (r < 512) ? r : (r + 512);      // rows: i(0..511), g(1024..1535), o(1536..2047)
    wa[idx] = f2b(Wih[(size_t)sr * 512 + c]);
  } else if (idx < nA + nB) {
    int j = idx - nA;
    int r = j / 768, c = j - r * 768;
    float v = (c < 512) ? Whh[(size_t)r * 512 + c] : Wih[(size_t)r * 512 + (c - 512)];
    wcat[j] = f2b(v);
  } else if (idx < nA + nB + nC) {
    int j = idx - nA - nB;
    wfc[j] = f2b(Wfc[j]);
  } else if (idx < nA + nB + nC + 2048) {
    int j = idx - nA - nB - nC;
    bias0[j] = bih[j] + bhh[j];
  }
}

// ---------------- prep_x0: step0 input, padded+selected, bf16 [B,512] ----------------
__global__ void prep_x0_kernel(const float* __restrict__ img, const float* __restrict__ txt,
                               const int* __restrict__ imask, const int* __restrict__ tmask,
                               unsigned short* __restrict__ X0) {
  int idx = blockIdx.x * blockDim.x + threadIdx.x;   // B*64 threads, 8 elems each
  int m = idx >> 6, seg = idx & 63;
  int s = (imask[m] == 0) ? 0 : ((tmask[m] == 0) ? 1 : 2);
  int kk = seg * 8;
  float4 v0 = {0.f, 0.f, 0.f, 0.f}, v1 = {0.f, 0.f, 0.f, 0.f};
  if (s == 0) {
    const float4* p = (const float4*)(img + (size_t)m * DIDIM + kk);
    v0 = p[0]; v1 = p[1];
  } else if (s == 1 && kk < DTDIM) {
    const float4* p = (const float4*)(txt + (size_t)m * DTDIM + kk);
    v0 = p[0]; v1 = p[1];
  }
  *(uint4*)(X0 + (size_t)m * DCDIM + kk) = pack8(v0, v1);
}

// ---------------- prepass: compact list of rows with both image & text present ----------------
__global__ void prepass_kernel(const int* __restrict__ imask, const int* __restrict__ tmask,
                               int* __restrict__ cnt, int* __restrict__ list) {
  int m = blockIdx.x * blockDim.x + threadIdx.x;
  if (m < BATCH) {
    if (imask[m] == 0 && tmask[m] == 0) {
      int p = atomicAdd(cnt, 1);
      list[p] = m;
    }
  }
}

// ---------------- phase A: step0 fused GEMM(i,g,o gates) + LSTM -> h1, c1 ----------------
// grid 8192 = jb(8) x my(1024); block 256 = 4 waves; rows m0..+63, cols j0..+63, 3 gate tiles.
__global__ __launch_bounds__(256) void phaseA_kernel(
    const unsigned short* __restrict__ X0,
    const int* __restrict__ imask, const int* __restrict__ tmask,
    const unsigned short* __restrict__ Wa, const float* __restrict__ bias0,
    unsigned short* __restrict__ h1, unsigned short* __restrict__ c1) {
  __shared__ __align__(16) char smem[50688];      // union: Xs(8K)+Ws(24K) | Gs 3*64*66*4
  char* xs = smem;              // 64 rows * 128B (granule-swizzled slots)
  char* wsm = smem + 8192;      // 192 rows * 128B
  float (*Gs)[64][66] = (float (*)[64][66])smem;

  int tid = threadIdx.x;
  int bx = blockIdx.x;
  int my = bx & 1023, jb = bx >> 10;
  int m0 = my * 64, j0 = jb * 64;
  int wave = tid >> 6, lane = tid & 63, lhi = lane >> 4, llo = lane & 15;

  floatx4 acc[4][3];
  floatx4 zz = {0.f, 0.f, 0.f, 0.f};
#pragma unroll
  for (int a = 0; a < 4; ++a)
#pragma unroll
    for (int b = 0; b < 3; ++b) acc[a][b] = zz;

  for (int kc = 0; kc < 8; ++kc) {
    // X stage: 8 chunks of 1KB; wave handles chunks wave*2+i.
    // lane -> lds row r=c*8+(lane>>3), slot lane&7 which must hold granule (slot)^(r&7)
#pragma unroll
    for (int i = 0; i < 2; ++i) {
      int c = wave * 2 + i;
      int r = c * 8 + (lane >> 3);
      int g = (lane & 7) ^ (r & 7);
      gload16(X0 + (size_t)(m0 + r) * DCDIM + kc * 64 + g * 8, xs + c * 1024);
    }
    // W stage: 24 chunks (192 rows = 3 gates x 64 cols)
#pragma unroll
    for (int i = 0; i < 6; ++i) {
      int c = wave * 6 + i;
      int rr = c * 8 + (lane >> 3);
      int g = (lane & 7) ^ (rr & 7);
      int lg = rr >> 6, jj = rr & 63;
      gload16(Wa + ((size_t)(lg * 512 + j0 + jj)) * 512 + kc * 64 + g * 8, wsm + c * 1024);
    }
    __syncthreads();
#pragma unroll
    for (int ks = 0; ks < 2; ++ks) {
      short8 afr[4];
#pragma unroll
      for (int ri = 0; ri < 4; ++ri) {
        int row = ri * 16 + llo;
        int sw = (ks * 4 + lhi) ^ (row & 7);
        afr[ri] = *(const short8*)(xs + row * 128 + sw * 16);
      }
#pragma unroll
      for (int s = 0; s < 3; ++s) {
        int u = 3 * wave + s;
        int lg = u >> 2, ci = u & 3;
        int rr = lg * 64 + ci * 16 + llo;
        int sw = (ks * 4 + lhi) ^ (rr & 7);
        short8 bfr = *(const short8*)(wsm + rr * 128 + sw * 16);
#pragma unroll
        for (int ri = 0; ri < 4; ++ri)
          acc[ri][s] = __builtin_amdgcn_mfma_f32_16x16x32_bf16(afr[ri], bfr, acc[ri][s], 0, 0, 0);
      }
    }
    __syncthreads();
  }
  // exchange gate tiles through LDS (each wave holds parts of different gates)
#pragma unroll
  for (int s = 0; s < 3; ++s) {
    int u = 3 * wave + s;
    int lg = u >> 2, ci = u & 3;
#pragma unroll
    for (int ri = 0; ri < 4; ++ri)
#pragma unroll
      for (int p = 0; p < 4; ++p)
        Gs[lg][ri * 16 + lhi * 4 + p][ci * 16 + llo] = acc[ri][s][p];
  }
  __syncthreads();
  {
    int m = tid >> 2;
    int gm = m0 + m;
    int jbase = (tid & 3) * 16;
    bool both = (imask[gm] == 0) && (tmask[gm] == 0);
    size_t rowoff = (size_t)gm * DCDIM + j0;
    unsigned hp[8], cp[8];
#pragma unroll
    for (int q = 0; q < 8; ++q) {
      float hv[2], cv[2];
#pragma unroll
      for (int t = 0; t < 2; ++t) {
        int jj = jbase + 2 * q + t;
        int j = j0 + jj;
        float iv = Gs[0][m][jj] + bias0[j];
        float gv = Gs[1][m][jj] + bias0[1024 + j];
        float ov = Gs[2][m][jj] + bias0[1536 + j];
        float iS = sigm(iv), gT = tanhf(gv), oS = sigm(ov);
        cv[t] = iS * gT;            // c0 = 0 -> f gate irrelevant in step 0
        hv[t] = oS * tanhf(cv[t]);
      }
      hp[q] = pack2(hv[0], hv[1]);
      cp[q] = pack2(cv[0], cv[1]);
    }
    uint4* hdst = (uint4*)(h1 + rowoff + jbase);
    hdst[0] = make_uint4(hp[0], hp[1], hp[2], hp[3]);
    hdst[1] = make_uint4(hp[4], hp[5], hp[6], hp[7]);
    if (both) {                     // c1 only consumed for both-rows (phaseB)
      uint4* cdst = (uint4*)(c1 + rowoff + jbase);
      cdst[0] = make_uint4(cp[0], cp[1], cp[2], cp[3]);
      cdst[1] = make_uint4(cp[4], cp[5], cp[6], cp[7]);
    }
  }
}

// ---------------- phase B: step1 (compacted to both-rows) -> h2 ----------------
// gates = [h1 | txt] @ [W_hh | W_ih[:,:256]]^T + bias0 ; K = 768; wave = gate
__global__ __launch_bounds__(256) void phaseB_kernel(
    const float* __restrict__ txt,
    const unsigned short* __restrict__ h1, const unsigned short* __restrict__ c1,
    const unsigned short* __restrict__ Wcat, const float* __restrict__ bias0,
    const int* __restrict__ cnt, const int* __restrict__ list,
    unsigned short* __restrict__ h2) {
  __shared__ __align__(16) char smem[67584];      // union: Xs(8K)+Ws(32K) | Gs 4*64*66*4
  __shared__ int rowmap[64];
  __shared__ int validr[64];
  char* xs = smem;
  char* wsm = smem + 8192;     // 256 rows * 128B
  float (*Gs)[64][66] = (float (*)[64][66])smem;

  int tid = threadIdx.x;
  int bx = blockIdx.x;
  int my = bx & 1023, jb = bx >> 10;
  int n = *cnt;
  int nbk = (n + 63) >> 6;
  if (my >= nbk) return;      // block-uniform early exit (compaction)
  int j0 = jb * 64;
  int wave = tid >> 6, lane = tid & 63, lhi = lane >> 4, llo = lane & 15;

  if (tid < 64) {
    int p = my * 64 + tid;
    int v = (p < n) ? 1 : 0;
    validr[tid] = v;
    rowmap[tid] = list[v ? p : 0];
  }
  __syncthreads();

  floatx4 acc[4][4];
  floatx4 zz = {0.f, 0.f, 0.f, 0.f};
#pragma unroll
  for (int a = 0; a < 4; ++a)
#pragma unroll
    for (int b = 0; b < 4; ++b) acc[a][b] = zz;

  for (int kc = 0; kc < 12; ++kc) {
    // X = [h1 | txt]: h1 part via gather gload_lds; txt part reg-staged (f32->bf16)
    if (kc < 8) {
#pragma unroll
      for (int i = 0; i < 2; ++i) {
        int c = wave * 2 + i;
        int r = c * 8 + (lane >> 3);
        int g = (lane & 7) ^ (r & 7);
        int gm = rowmap[r];
        gload16(h1 + (size_t)gm * DCDIM + kc * 64 + g * 8, xs + c * 1024);
      }
    } else {
#pragma unroll
      for (int i2 = 0; i2 < 2; ++i2) {
        int f = i2 * 256 + tid;
        int r = f >> 3, sw = f & 7, g = sw ^ (r & 7);
        int gm = rowmap[r];
        int kk = (kc - 8) * 64 + g * 8;
        const float4* p = (const float4*)(txt + (size_t)gm * DTDIM + kk);
        *(uint4*)(xs + r * 128 + sw * 16) = pack8(p[0], p[1]);
      }
    }
    // W stage: 32 chunks (256 rows = 4 gates x 64 cols), row length 768
#pragma unroll
    for (int i = 0; i < 8; ++i) {
      int c = wave * 8 + i;
      int rr = c * 8 + (lane >> 3);
      int g = (lane & 7) ^ (rr & 7);
      int gg = rr >> 6, jj = rr & 63;
      gload16(Wcat + ((size_t)(gg * 512 + j0 + jj)) * 768 + kc * 64 + g * 8, wsm + c * 1024);
    }
    __syncthreads();
#pragma unroll
    for (int ks = 0; ks < 2; ++ks) {
      short8 afr[4];
#pragma unroll
      for (int ri = 0; ri < 4; ++ri) {
        int row = ri * 16 + llo;
        int sw = (ks * 4 + lhi) ^ (row & 7);
        afr[ri] = *(const short8*)(xs + row * 128 + sw * 16);
      }
#pragma unroll
      for (int ci = 0; ci < 4; ++ci) {
        int rr = wave * 64 + ci * 16 + llo;
        int sw = (ks * 4 + lhi) ^ (rr & 7);
        short8 bfr = *(const short8*)(wsm + rr * 128 + sw * 16);
#pragma unroll
        for (int ri = 0; ri < 4; ++ri)
          acc[ri][ci] = __builtin_amdgcn_mfma_f32_16x16x32_bf16(afr[ri], bfr, acc[ri][ci], 0, 0, 0);
      }
    }
    __syncthreads();
  }
#pragma unroll
  for (int ci = 0; ci < 4; ++ci)
#pragma unroll
    for (int ri = 0; ri < 4; ++ri)
#pragma unroll
      for (int p = 0; p < 4; ++p)
        Gs[wave][ri * 16 + lhi * 4 + p][ci * 16 + llo] = acc[ri][ci][p];
  __syncthreads();
  {
    int m = tid >> 2;
    if (validr[m]) {
      int gm = rowmap[m];
      int jbase = (tid & 3) * 16;
      // vector-load c1 segment (written only for both-rows)
      const uint4* csrc = (const uint4*)(c1 + (size_t)gm * DCDIM + j0 + jbase);
      uint4 cq0 = csrc[0], cq1 = csrc[1];
      unsigned cw[8] = {cq0.x, cq0.y, cq0.z, cq0.w, cq1.x, cq1.y, cq1.z, cq1.w};
      unsigned hp[8];
#pragma unroll
      for (int q = 0; q < 8; ++q) {
        float hv[2];
#pragma unroll
        for (int t = 0; t < 2; ++t) {
          int jj = jbase + 2 * q + t;
          int j = j0 + jj;
          float iv = Gs[0][m][jj] + bias0[j];
          float fv = Gs[1][m][jj] + bias0[512 + j];
          float gv = Gs[2][m][jj] + bias0[1024 + j];
          float ov = Gs[3][m][jj] + bias0[1536 + j];
          float iS = sigm(iv), fS = sigm(fv), gT = tanhf(gv), oS = sigm(ov);
          float c1v = b2f((unsigned short)((cw[q] >> (16 * t)) & 0xFFFFu));
          float c2 = fS * c1v + iS * gT;
          hv[t] = oS * tanhf(c2);
        }
        hp[q] = pack2(hv[0], hv[1]);
      }
      uint4* hdst = (uint4*)(h2 + (size_t)gm * DCDIM + j0 + jbase);
      hdst[0] = make_uint4(hp[0], hp[1], hp[2], hp[3]);
      hdst[1] = make_uint4(hp[4], hp[5], hp[6], hp[7]);
    }
  }
}

// ---------------- phase C: out = h_final @ W_fc^T + b_fc ----------------
// per block: 64 rows x 128 out-cols; wave w covers col-frags {2w, 2w+1}
__global__ __launch_bounds__(256) void phaseC_kernel(
    const int* __restrict__ imask, const int* __restrict__ tmask,
    const unsigned short* __restrict__ h1, const unsigned short* __restrict__ h2,
    const unsigned short* __restrict__ Wfc, const float* __restrict__ bfc,
    float* __restrict__ out) {
  __shared__ __align__(16) char smem[24576];   // Xs 8K + Ws 16K
  __shared__ int both[64];
  char* xs = smem;
  char* wsm = smem + 8192;    // 128 rows * 128B
  int tid = threadIdx.x;
  int bx = blockIdx.x;
  int my = bx & 1023, nb = bx >> 10;
  int m0 = my * 64, n0 = nb * 128;
  int wave = tid >> 6, lane = tid & 63, lhi = lane >> 4, llo = lane & 15;
  if (tid < 64) {
    int m = m0 + tid;
    both[tid] = (imask[m] == 0 && tmask[m] == 0) ? 1 : 0;
  }
  __syncthreads();

  floatx4 acc[4][2];
  floatx4 zz = {0.f, 0.f, 0.f, 0.f};
#pragma unroll
  for (int a = 0; a < 4; ++a) { acc[a][0] = zz; acc[a][1] = zz; }

  for (int kc = 0; kc < 8; ++kc) {
#pragma unroll
    for (int i = 0; i < 2; ++i) {
      int c = wave * 2 + i;
      int r = c * 8 + (lane >> 3);
      int g = (lane & 7) ^ (r & 7);
      const unsigned short* base = both[r] ? h2 : h1;
      gload16(base + (size_t)(m0 + r) * DCDIM + kc * 64 + g * 8, xs + c * 1024);
    }
#pragma unroll
    for (int i = 0; i < 4; ++i) {
      int c = wave * 4 + i;
      int rr = c * 8 + (lane >> 3);
      int g = (lane & 7) ^ (rr & 7);
      gload16(Wfc + ((size_t)(n0 + rr)) * 512 + kc * 64 + g * 8, wsm + c * 1024);
    }
    __syncthreads();
#pragma unroll
    for (int ks = 0; ks < 2; ++ks) {
      short8 afr[4];
#pragma unroll
      for (int ri = 0; ri < 4; ++ri) {
        int row = ri * 16 + llo;
        int sw = (ks * 4 + lhi) ^ (row & 7);
        afr[ri] = *(const short8*)(xs + row * 128 + sw * 16);
      }
#pragma unroll
      for (int cl = 0; cl < 2; ++cl) {
        int rr = (wave * 2 + cl) * 16 + llo;
        int sw = (ks * 4 + lhi) ^ (rr & 7);
        short8 bfr = *(const short8*)(wsm + rr * 128 + sw * 16);
#pragma unroll
        for (int ri = 0; ri < 4; ++ri)
          acc[ri][cl] = __builtin_amdgcn_mfma_f32_16x16x32_bf16(afr[ri], bfr, acc[ri][cl], 0, 0, 0);
      }
    }
    __syncthreads();
  }
#pragma unroll
  for (int cl = 0; cl < 2; ++cl) {
    int nn = n0 + (wave * 2 + cl) * 16 + llo;
    float bb = bfc[nn];
#pragma unroll
    for (int ri = 0; ri < 4; ++ri)
#pragma unroll
      for (int p = 0; p < 4; ++p) {
        int mm = m0 + ri * 16 + lhi * 4 + p;
        out[(size_t)mm * 1024 + nn] = acc[ri][cl][p] + bb;
      }
  }
}

// ---------------- launcher ----------------
extern "C" void kernel_launch(void* const* d_in, const int* in_sizes, int n_in,
                              void* d_out, int out_size, void* d_ws, size_t ws_size,
                              hipStream_t stream) {
  const float* img  = (const float*)d_in[0];
  const float* txt  = (const float*)d_in[1];
  const int* imask  = (const int*)d_in[2];
  const int* tmask  = (const int*)d_in[3];
  const float* Wih  = (const float*)d_in[4];
  const float* Whh  = (const float*)d_in[5];
  const float* bih  = (const float*)d_in[6];
  const float* bhh  = (const float*)d_in[7];
  const float* Wfc  = (const float*)d_in[8];
  const float* bfc  = (const float*)d_in[9];
  float* out = (float*)d_out;

  char* ws = (char*)d_ws;
  unsigned short* wa   = (unsigned short*)(ws + WS_WA);
  unsigned short* wcat = (unsigned short*)(ws + WS_WCAT);
  unsigned short* wfc  = (unsigned short*)(ws + WS_WFC);
  float* bias0         = (float*)(ws + WS_BIAS);
  int* cnt             = (int*)(ws + WS_CNT);
  int* list            = (int*)(ws + WS_LIST);
  unsigned short* h1   = (unsigned short*)(ws + WS_H1);
  unsigned short* c1   = (unsigned short*)(ws + WS_C1);
  unsigned short* h2   = (unsigned short*)(ws + WS_H2);
  unsigned short* X0   = (unsigned short*)(ws + WS_H2);   // alias: X0 dead before h2 born

  prep_kernel<<<11272, 256, 0, stream>>>(Wih, Whh, bih, bhh, Wfc, wa, wcat, wfc, bias0, cnt);
  prep_x0_kernel<<<16384, 256, 0, stream>>>(img, txt, imask, tmask, X0);
  prepass_kernel<<<256, 256, 0, stream>>>(imask, tmask, cnt, list);
  phaseA_kernel<<<8192, 256, 0, stream>>>(X0, imask, tmask, wa, bias0, h1, c1);
  phaseB_kernel<<<8192, 256, 0, stream>>>(txt, h1, c1, wcat, bias0, cnt, list, h2);
  phaseC_kernel<<<8192, 256, 0, stream>>>(imask, tmask, h1, h2, wfc, bfc, out);
}